// Round 12
// baseline (11003.175 us; speedup 1.0000x reference)
//
#include <hip/hip_runtime.h>

// Round 12: output dtype fix. d_out is FP32 (the "(bf16" in the fail label is
// a hardcoded literal; the reader branches on out_dtype_str). Faithful listing
// math: Q/K/V/O projections x @ W.T + b, contiguous head split, scores/8,
// mask==0 -> -10000, softmax over keys. Inputs fp32, mask int32, out fp32.

#define B_  2
#define L_  4096
#define D_  512
#define H_  8
#define BH_ 16
#define M_  8192

// ---------------------------------------------------------------------------
// Q/K/V projection, x @ W.T (row dot). grid (L/4, chunk, 3);
// block 256 = 4 l-rows x 64 dims. dst per chunk-slot: (L, 64) fp32.
// ---------------------------------------------------------------------------
__global__ __launch_bounds__(256) void qkvproj(
    const float* __restrict__ x,
    const float* __restrict__ Wq, const float* __restrict__ bq,
    const float* __restrict__ Wk, const float* __restrict__ bk,
    const float* __restrict__ Wv, const float* __restrict__ bv,
    float* __restrict__ Qw, float* __restrict__ Kw, float* __restrict__ Vw,
    int bh0)
{
    __shared__ float xs[4][512];

    const int t  = threadIdx.x;
    const int bh = bh0 + blockIdx.y, b = bh >> 3, h = bh & 7;
    const int l0 = blockIdx.x * 4;

    const float* W; const float* bi; float* dst;
    if      (blockIdx.z == 0) { W = Wq; bi = bq; dst = Qw; }
    else if (blockIdx.z == 1) { W = Wk; bi = bk; dst = Kw; }
    else                      { W = Wv; bi = bv; dst = Vw; }

    const size_t xbase = ((size_t)b * L_ + l0) * 512;
    for (int i = t; i < 2048; i += 256)
        xs[i >> 9][i & 511] = x[xbase + i];
    __syncthreads();

    const int li = t >> 6, d = t & 63;
    const int wrow = h * 64 + d;                // output feature = ROW of W
    const float* wr = W + (size_t)wrow * 512;
    float a0 = 0.f, a1 = 0.f, a2 = 0.f, a3 = 0.f;
    for (int k = 0; k < 512; k += 4) {
        const float4 w4 = *(const float4*)(wr + k);
        a0 += xs[li][k]     * w4.x;  a1 += xs[li][k + 1] * w4.y;
        a2 += xs[li][k + 2] * w4.z;  a3 += xs[li][k + 3] * w4.w;
    }
    const float acc = (a0 + a1) + (a2 + a3) + bi[wrow];
    dst[((size_t)blockIdx.y * L_ + l0 + li) * 64 + d] = acc;
}

// ---------------------------------------------------------------------------
// VALU flash attention: one thread per (bh, q). grid (L/256, chunk).
// mask==0 -> -10000 (faithful). Writes FP32 to O (B, L, 512).
// ---------------------------------------------------------------------------
__global__ __launch_bounds__(256, 1) void vattn(
    const float* __restrict__ Qw, const float* __restrict__ Kw,
    const float* __restrict__ Vw, const int* __restrict__ mask,
    float* __restrict__ O, int bh0)
{
    __shared__ float Ks[64][68];
    __shared__ float Vs[64][68];
    __shared__ float Ms[64];   // 1.0 = masked (mask==0)

    const int t    = threadIdx.x;
    const int slot = blockIdx.y;
    const int bh   = bh0 + slot, b = bh >> 3, h = bh & 7;
    const int q    = blockIdx.x * 256 + t;

    float qv[64];
    const size_t qoff = ((size_t)slot * L_ + q) * 64;
#pragma unroll
    for (int d = 0; d < 64; ++d) qv[d] = Qw[qoff + d];

    float m_i = -1e30f, l_i = 0.f;
    float ov[64];
#pragma unroll
    for (int d = 0; d < 64; ++d) ov[d] = 0.f;
    float s[64];

    for (int kt = 0; kt < 64; ++kt) {
        const int k0 = kt * 64;
        const size_t koff = ((size_t)slot * L_ + k0) * 64;
        __syncthreads();
        for (int i = t; i < 4096; i += 256) {
            Ks[i >> 6][i & 63] = Kw[koff + i];
            Vs[i >> 6][i & 63] = Vw[koff + i];
        }
        if (t < 64) Ms[t] = (mask[b * L_ + k0 + t] == 0) ? 1.f : 0.f;
        __syncthreads();

        float mx = -1e30f;
#pragma unroll
        for (int kk = 0; kk < 64; ++kk) {
            float a0 = 0.f, a1 = 0.f, a2 = 0.f, a3 = 0.f;
#pragma unroll
            for (int d = 0; d < 64; d += 4) {
                const float4 k4 = *(const float4*)(&Ks[kk][d]);
                a0 += qv[d] * k4.x;     a1 += qv[d + 1] * k4.y;
                a2 += qv[d + 2] * k4.z; a3 += qv[d + 3] * k4.w;
            }
            const float sv = (Ms[kk] != 0.f) ? -10000.f
                                             : ((a0 + a1) + (a2 + a3)) * 0.125f;
            s[kk] = sv;
            mx = fmaxf(mx, sv);
        }
        const float mnew  = fmaxf(m_i, mx);
        const float alpha = __expf(m_i - mnew);
        float ss = 0.f;
#pragma unroll
        for (int kk = 0; kk < 64; ++kk) {
            const float p = __expf(s[kk] - mnew);
            s[kk] = p;
            ss += p;
        }
        l_i = l_i * alpha + ss;
        m_i = mnew;
#pragma unroll
        for (int d = 0; d < 64; ++d) ov[d] *= alpha;
#pragma unroll
        for (int kk = 0; kk < 64; ++kk) {
            const float p = s[kk];
#pragma unroll
            for (int d = 0; d < 64; d += 4) {
                const float4 v4 = *(const float4*)(&Vs[kk][d]);
                ov[d]     += p * v4.x;  ov[d + 1] += p * v4.y;
                ov[d + 2] += p * v4.z;  ov[d + 3] += p * v4.w;
            }
        }
    }

    const float inv = 1.f / l_i;
    const size_t ooff = ((size_t)b * L_ + q) * 512 + h * 64;
#pragma unroll
    for (int d = 0; d < 64; ++d) O[ooff + d] = ov[d] * inv;
}

// ---------------------------------------------------------------------------
// In-place FP32 output projection: AO = AO @ Wo.T + bo, (M,512).
// One block per 16 rows; rows fully staged in LDS (32 KB) before any write.
// Thread layout: row = t>>4 (16 rows), col-group = (t&15)*32 (+32 cols).
// ---------------------------------------------------------------------------
__global__ __launch_bounds__(256) void voutproj(
    float* __restrict__ AO,
    const float* __restrict__ Wo, const float* __restrict__ bo)
{
    __shared__ float As[16][512];

    const int t  = threadIdx.x;
    const int bm = blockIdx.x * 16;

#pragma unroll
    for (int it = 0; it < 8; ++it) {
        const int idx = (t + it * 256) * 4;        // 0..8191 step 4
        const int row = idx >> 9, c = idx & 511;
        *(float4*)(&As[row][c]) = *(const float4*)(AO + (size_t)(bm + row) * 512 + c);
    }
    __syncthreads();

    const int row = t >> 4;
    const int n0  = (t & 15) * 32;
    for (int j = 0; j < 32; ++j) {
        const int n = n0 + j;                      // output feature = ROW of Wo
        const float* wr = Wo + (size_t)n * 512;
        float a0 = 0.f, a1 = 0.f, a2 = 0.f, a3 = 0.f;
        for (int k = 0; k < 512; k += 4) {
            const float4 w4 = *(const float4*)(wr + k);
            a0 += As[row][k]     * w4.x;  a1 += As[row][k + 1] * w4.y;
            a2 += As[row][k + 2] * w4.z;  a3 += As[row][k + 3] * w4.w;
        }
        AO[(size_t)(bm + row) * 512 + n] = (a0 + a1) + (a2 + a3) + bo[n];
    }
}

extern "C" void kernel_launch(void* const* d_in, const int* in_sizes, int n_in,
                              void* d_out, int out_size, void* d_ws, size_t ws_size,
                              hipStream_t stream) {
    const float* x    = (const float*)d_in[0];
    const int*   mask = (const int*)d_in[1];
    const float* Wq = (const float*)d_in[2]; const float* bq = (const float*)d_in[3];
    const float* Wk = (const float*)d_in[4]; const float* bk = (const float*)d_in[5];
    const float* Wv = (const float*)d_in[6]; const float* bv = (const float*)d_in[7];
    const float* Wo = (const float*)d_in[8]; const float* bo = (const float*)d_in[9];

    float* out = (float*)d_out;
    char*  ws  = (char*)d_ws;

    const size_t per_bh = (size_t)3 * L_ * 64 * 4;   // fp32 Q+K+V per bh = 3 MiB
    int chunk = 16;
    while (chunk > 1 && (size_t)chunk * per_bh > ws_size) chunk >>= 1;

    float* Qw = (float*)ws;
    float* Kw = Qw + (size_t)chunk * L_ * 64;
    float* Vw = Kw + (size_t)chunk * L_ * 64;

    for (int bh0 = 0; bh0 < BH_; bh0 += chunk) {
        qkvproj<<<dim3(L_ / 4, chunk, 3), 256, 0, stream>>>(
            x, Wq, bq, Wk, bk, Wv, bv, Qw, Kw, Vw, bh0);
        vattn<<<dim3(L_ / 256, chunk), 256, 0, stream>>>(
            Qw, Kw, Vw, mask, out, bh0);
    }
    voutproj<<<dim3(M_ / 16), 256, 0, stream>>>(out, Wo, bo);
}

// Round 13
// 543.943 us; speedup vs baseline: 20.2285x; 20.2285x over previous
//
#include <hip/hip_runtime.h>

// Round 13: MFMA bf16-compute pipeline (round-4 structure, validated by
// consistency with the passing fp32 round-12), with certified fp32 I/O:
// inputs fp32 (converted to bf16 on LDS stage), accum fp32, output fp32.
//   kvproj : K,V = x @ {Wk,Wv}^T + b -> ws bf16 (chunk,L,64)
//   attn   : Q-proj fused; flash attention; fp32 out (B,L,512)
//   outproj: d_out = d_out @ Wo^T + bo, in-place fp32 (32-row LDS stage)

#define B_  2
#define L_  4096
#define D_  512
#define H_  8
#define BH_ 16
#define M_  8192

typedef __attribute__((ext_vector_type(8))) short short8;    // 8 bf16 = 4 VGPR
typedef __attribute__((ext_vector_type(4))) float f32x4;
typedef unsigned short u16;

static __device__ __forceinline__ u16 f2b(float f) {
    union { float f; unsigned i; } x; x.f = f;
    unsigned r = x.i + 0x7fff + ((x.i >> 16) & 1);   // RNE
    return (u16)(r >> 16);
}

// Stage 8 consecutive fp32 -> 8 bf16 (16 B) into LDS.
static __device__ __forceinline__ void stage8f(u16* dst, const float* s) {
    const float4 a = *(const float4*)s;
    const float4 b = *(const float4*)(s + 4);
    u16 tmp[8] = { f2b(a.x), f2b(a.y), f2b(a.z), f2b(a.w),
                   f2b(b.x), f2b(b.y), f2b(b.z), f2b(b.w) };
    *(uint4*)dst = *(const uint4*)tmp;
}

// ---------------------------------------------------------------------------
// K/V projection. grid (chunk, L/64, 2) z=0->K,1->V. Block 64x64 tile,
// 4 waves 2x2. out per bh: (L,64) bf16 row-major.
// ---------------------------------------------------------------------------
__global__ __launch_bounds__(256) void kvproj_kernel(
    const float* __restrict__ x,
    const float* __restrict__ Wk, const float* __restrict__ bk,
    const float* __restrict__ Wv, const float* __restrict__ bv,
    u16* __restrict__ Kws, u16* __restrict__ Vws, int bh0)
{
    __shared__ __align__(16) u16 As[64][40];   // 80 B rows: 2-way alias free
    __shared__ __align__(16) u16 Bs[64][40];

    const int t    = threadIdx.x;
    const int wid  = t >> 6, lane = t & 63;
    const int m15  = lane & 15, quad = lane >> 4;
    const int wm   = wid >> 1, wn = wid & 1;

    const int bh = bh0 + blockIdx.x;
    const int b  = bh >> 3, h = bh & 7;
    const int l0 = blockIdx.y * 64;
    const float* W  = blockIdx.z ? Wv : Wk;
    const float* bi = blockIdx.z ? bv : bk;
    u16* out = (blockIdx.z ? Vws : Kws) + (size_t)blockIdx.x * (L_ * 64);

    const int lrow = t >> 2;        // 0..63
    const int lcol = (t & 3) * 8;   // 0,8,16,24
    const size_t xrow0 = (size_t)b * L_ + l0;

    f32x4 acc[2][2] = {};

    for (int k0 = 0; k0 < 512; k0 += 32) {
        __syncthreads();
        stage8f(&As[lrow][lcol], x + (xrow0 + lrow) * 512 + k0 + lcol);
        stage8f(&Bs[lrow][lcol], W + (size_t)(h * 64 + lrow) * 512 + k0 + lcol);
        __syncthreads();

        short8 afr[2], bfr[2];
#pragma unroll
        for (int mi = 0; mi < 2; ++mi)
            afr[mi] = *(const short8*)(&As[wm * 32 + mi * 16 + m15][quad * 8]);
#pragma unroll
        for (int ni = 0; ni < 2; ++ni)
            bfr[ni] = *(const short8*)(&Bs[wn * 32 + ni * 16 + m15][quad * 8]);
#pragma unroll
        for (int mi = 0; mi < 2; ++mi)
#pragma unroll
            for (int ni = 0; ni < 2; ++ni)
                acc[mi][ni] = __builtin_amdgcn_mfma_f32_16x16x32_bf16(
                    afr[mi], bfr[ni], acc[mi][ni], 0, 0, 0);
    }

#pragma unroll
    for (int mi = 0; mi < 2; ++mi)
#pragma unroll
        for (int ni = 0; ni < 2; ++ni) {
            const int d  = wn * 32 + ni * 16 + m15;
            const float bv_ = bi[h * 64 + d];
#pragma unroll
            for (int r = 0; r < 4; ++r) {
                const int l = l0 + wm * 32 + mi * 16 + quad * 4 + r;
                out[(size_t)l * 64 + d] = f2b(acc[mi][ni][r] + bv_);
            }
        }
}

// ---------------------------------------------------------------------------
// Fused Q-projection + flash attention. grid (L/64, chunk).
// Block = 4 waves; wave w owns q-rows [16w, 16w+16). Writes fp32 O (B,L,512).
// ---------------------------------------------------------------------------
__global__ __launch_bounds__(256) void attn_kernel(
    const float* __restrict__ x,
    const float* __restrict__ Wq, const float* __restrict__ bq,
    const u16* __restrict__ Kws, const u16* __restrict__ Vws,
    const int* __restrict__ mask,
    float* __restrict__ O, int bh0)
{
    __shared__ __align__(16) u16 xs [64][40];
    __shared__ __align__(16) u16 wqs[64][40];
    __shared__ __align__(16) u16 Qs [64][72];
    __shared__ __align__(16) u16 Ks [64][72];  // [key][dim]
    __shared__ __align__(16) u16 Vts[64][72];  // [dim][key]
    __shared__ __align__(16) u16 Ps [4][16][72];
    __shared__ float Ms[64];     // 1.0 = masked (mask==0)

    const int t    = threadIdx.x;
    const int wid  = t >> 6, lane = t & 63;
    const int m15  = lane & 15, quad = lane >> 4;

    const int bh = bh0 + blockIdx.y;
    const int b  = bh >> 3, h = bh & 7;
    const int q0 = blockIdx.x * 64;
    const u16* Kc = Kws + (size_t)blockIdx.y * (L_ * 64);
    const u16* Vc = Vws + (size_t)blockIdx.y * (L_ * 64);

    const int lrow = t >> 2;
    const int lcol = (t & 3) * 8;

    // ---- fused Q projection: Q[64][64] = x[q-tile] @ Wq[h-rows]^T + bq ----
    f32x4 qacc[4] = {};
    for (int k0 = 0; k0 < 512; k0 += 32) {
        __syncthreads();
        stage8f(&xs [lrow][lcol], x  + ((size_t)b * L_ + q0 + lrow) * 512 + k0 + lcol);
        stage8f(&wqs[lrow][lcol], Wq + (size_t)(h * 64 + lrow) * 512 + k0 + lcol);
        __syncthreads();
        const short8 afr = *(const short8*)(&xs[wid * 16 + m15][quad * 8]);
#pragma unroll
        for (int ni = 0; ni < 4; ++ni) {
            const short8 bfr = *(const short8*)(&wqs[ni * 16 + m15][quad * 8]);
            qacc[ni] = __builtin_amdgcn_mfma_f32_16x16x32_bf16(afr, bfr, qacc[ni], 0, 0, 0);
        }
    }
    // C-layout -> LDS -> A-frags (wave-local round trip, DS in-order per wave)
#pragma unroll
    for (int ni = 0; ni < 4; ++ni) {
        const float bv_ = bq[h * 64 + ni * 16 + m15];
#pragma unroll
        for (int r = 0; r < 4; ++r)
            Qs[wid * 16 + quad * 4 + r][ni * 16 + m15] = f2b(qacc[ni][r] + bv_);
    }
    short8 qf[2];
#pragma unroll
    for (int kc = 0; kc < 2; ++kc)
        qf[kc] = *(const short8*)(&Qs[wid * 16 + m15][kc * 32 + quad * 8]);

    // ---- flash loop over 64-key tiles ----
    float m_i[4], l_i[4];
#pragma unroll
    for (int r = 0; r < 4; ++r) { m_i[r] = -1e30f; l_i[r] = 0.0f; }
    f32x4 oacc[4] = {};

    for (int kt = 0; kt < 64; ++kt) {
        const int k0 = kt * 64;
        __syncthreads();
#pragma unroll
        for (int i = 0; i < 2; ++i) {
            const int c   = t + i * 256;       // 0..511
            const int row = c >> 3;            // key 0..63
            const int col = (c & 7) * 8;       // dim start
            *(uint4*)(&Ks[row][col]) = *(const uint4*)(Kc + (size_t)(k0 + row) * 64 + col);
            union { uint4 v; u16 u[8]; } vv;
            vv.v = *(const uint4*)(Vc + (size_t)(k0 + row) * 64 + col);
#pragma unroll
            for (int j = 0; j < 8; ++j) Vts[col + j][row] = vv.u[j];
        }
        if (t < 64) Ms[t] = (mask[b * L_ + k0 + t] == 0) ? 1.0f : 0.0f;
        __syncthreads();

        // S = Q K^T / 8, C-layout; masked -> -10000
        float s[4][4];
#pragma unroll
        for (int ni = 0; ni < 4; ++ni) {
            f32x4 sa = {};
#pragma unroll
            for (int kc = 0; kc < 2; ++kc) {
                const short8 bf = *(const short8*)(&Ks[ni * 16 + m15][kc * 32 + quad * 8]);
                sa = __builtin_amdgcn_mfma_f32_16x16x32_bf16(qf[kc], bf, sa, 0, 0, 0);
            }
            const float msk = Ms[ni * 16 + m15];
#pragma unroll
            for (int r = 0; r < 4; ++r)
                s[ni][r] = (msk != 0.0f) ? -10000.0f : sa[r] * 0.125f;
        }

        // online softmax per q-row (16 lanes of a quad share a row)
        float alpha[4];
#pragma unroll
        for (int r = 0; r < 4; ++r) {
            float mx = fmaxf(fmaxf(s[0][r], s[1][r]), fmaxf(s[2][r], s[3][r]));
#pragma unroll
            for (int off = 1; off < 16; off <<= 1)
                mx = fmaxf(mx, __shfl_xor(mx, off));
            const float mnew = fmaxf(m_i[r], mx);
            alpha[r] = __expf(m_i[r] - mnew);
            m_i[r] = mnew;
            float ss = 0.0f;
#pragma unroll
            for (int ni = 0; ni < 4; ++ni) {
                const float p = __expf(s[ni][r] - mnew);
                s[ni][r] = p;
                ss += p;
            }
#pragma unroll
            for (int off = 1; off < 16; off <<= 1)
                ss += __shfl_xor(ss, off);
            l_i[r] = l_i[r] * alpha[r] + ss;
        }

        // P: C-layout -> LDS -> A-frags (wave-local slice)
#pragma unroll
        for (int ni = 0; ni < 4; ++ni)
#pragma unroll
            for (int r = 0; r < 4; ++r)
                Ps[wid][quad * 4 + r][ni * 16 + m15] = f2b(s[ni][r]);
        short8 pf[2];
#pragma unroll
        for (int kc2 = 0; kc2 < 2; ++kc2)
            pf[kc2] = *(const short8*)(&Ps[wid][m15][kc2 * 32 + quad * 8]);

        // O = alpha*O + P V
#pragma unroll
        for (int ni = 0; ni < 4; ++ni) {
#pragma unroll
            for (int r = 0; r < 4; ++r) oacc[ni][r] *= alpha[r];
#pragma unroll
            for (int kc2 = 0; kc2 < 2; ++kc2) {
                const short8 vf = *(const short8*)(&Vts[ni * 16 + m15][kc2 * 32 + quad * 8]);
                oacc[ni] = __builtin_amdgcn_mfma_f32_16x16x32_bf16(pf[kc2], vf, oacc[ni], 0, 0, 0);
            }
        }
    }

    // epilogue: O /= l -> fp32 (B, L, 512)
#pragma unroll
    for (int ni = 0; ni < 4; ++ni)
#pragma unroll
        for (int r = 0; r < 4; ++r) {
            const int qrow = q0 + wid * 16 + quad * 4 + r;
            O[((size_t)b * L_ + qrow) * 512 + h * 64 + ni * 16 + m15] =
                oacc[ni][r] / l_i[r];
        }
}

// ---------------------------------------------------------------------------
// In-place fp32 output projection: AO = AO @ Wo^T + bo, (M,512).
// Block per 32 rows; A-slab fully staged (as bf16) before any global write.
// ---------------------------------------------------------------------------
__global__ __launch_bounds__(256) void outproj_kernel(
    float* __restrict__ AO,
    const float* __restrict__ Wo, const float* __restrict__ bo)
{
    __shared__ __align__(16) u16 As[32][520];
    __shared__ __align__(16) u16 Ws_[64][40];

    const int t    = threadIdx.x;
    const int wid  = t >> 6, lane = t & 63;
    const int m15  = lane & 15, quad = lane >> 4;
    const int wm   = wid >> 1, wn = wid & 1;
    const int bm   = blockIdx.x * 32;

#pragma unroll
    for (int it = 0; it < 8; ++it) {
        const int idx = t + it * 256;            // 0..2047
        const int row = idx >> 6, c8 = (idx & 63) * 8;
        stage8f(&As[row][c8], AO + (size_t)(bm + row) * 512 + c8);
    }
    const int lrow = t >> 2;
    const int lcol = (t & 3) * 8;
    __syncthreads();

    for (int n0 = 0; n0 < 512; n0 += 64) {
        f32x4 acc[2] = {};
        for (int k0 = 0; k0 < 512; k0 += 32) {
            __syncthreads();
            stage8f(&Ws_[lrow][lcol], Wo + (size_t)(n0 + lrow) * 512 + k0 + lcol);
            __syncthreads();
            const short8 afr = *(const short8*)(&As[wm * 16 + m15][k0 + quad * 8]);
#pragma unroll
            for (int ni = 0; ni < 2; ++ni) {
                const short8 bfr = *(const short8*)(&Ws_[wn * 32 + ni * 16 + m15][quad * 8]);
                acc[ni] = __builtin_amdgcn_mfma_f32_16x16x32_bf16(afr, bfr, acc[ni], 0, 0, 0);
            }
        }
#pragma unroll
        for (int ni = 0; ni < 2; ++ni) {
            const int col = n0 + wn * 32 + ni * 16 + m15;
            const float bv_ = bo[col];
#pragma unroll
            for (int r = 0; r < 4; ++r) {
                const int row = bm + wm * 16 + quad * 4 + r;
                AO[(size_t)row * 512 + col] = acc[ni][r] + bv_;
            }
        }
    }
}

extern "C" void kernel_launch(void* const* d_in, const int* in_sizes, int n_in,
                              void* d_out, int out_size, void* d_ws, size_t ws_size,
                              hipStream_t stream) {
    const float* x    = (const float*)d_in[0];
    const int*   mask = (const int*)d_in[1];
    const float* Wq = (const float*)d_in[2]; const float* bq = (const float*)d_in[3];
    const float* Wk = (const float*)d_in[4]; const float* bk = (const float*)d_in[5];
    const float* Wv = (const float*)d_in[6]; const float* bv = (const float*)d_in[7];
    const float* Wo = (const float*)d_in[8]; const float* bo = (const float*)d_in[9];

    float* out = (float*)d_out;
    u16*   ws  = (u16*)d_ws;

    // bf16 K+V per bh = 1 MiB; adaptive chunk (ws certified >= 3 MiB).
    const size_t per_bh = (size_t)2 * L_ * 64 * 2;
    int chunk = 16;
    while (chunk > 1 && (size_t)chunk * per_bh > ws_size) chunk >>= 1;

    u16* Kws = ws;
    u16* Vws = Kws + (size_t)chunk * (L_ * 64);

    for (int bh0 = 0; bh0 < BH_; bh0 += chunk) {
        kvproj_kernel<<<dim3(chunk, L_ / 64, 2), 256, 0, stream>>>(
            x, Wk, bk, Wv, bv, Kws, Vws, bh0);
        attn_kernel<<<dim3(L_ / 64, chunk), 256, 0, stream>>>(
            x, Wq, bq, Kws, Vws, mask, out, bh0);
    }
    outproj_kernel<<<dim3(M_ / 32), 256, 0, stream>>>(out, Wo, bo);
}

// Round 14
// 442.858 us; speedup vs baseline: 24.8459x; 1.2283x over previous
//
#include <hip/hip_runtime.h>

// Round 14: attn optimization. (1) V pre-transposed in kvproj (LDS bounce,
// pad-73 anti-conflict) -> attn stages Vt with plain uint4 copies (was: 16
// scalar u16 writes/thread/k-tile re-done 64x per tile, 8e7 conflict cycles).
// (2) Q-tile 128 (2 A-frags/wave) -> 32 MFMA/wave/k-tile, 2x density.
// (3) Q pre-scaled by 1/8 (exact in bf16). fp32 I/O, bf16 MFMA compute.

#define B_  2
#define L_  4096
#define D_  512
#define H_  8
#define BH_ 16
#define M_  8192

typedef __attribute__((ext_vector_type(8))) short short8;    // 8 bf16 = 4 VGPR
typedef __attribute__((ext_vector_type(4))) float f32x4;
typedef unsigned short u16;

static __device__ __forceinline__ u16 f2b(float f) {
    union { float f; unsigned i; } x; x.f = f;
    unsigned r = x.i + 0x7fff + ((x.i >> 16) & 1);   // RNE
    return (u16)(r >> 16);
}

// Stage 8 consecutive fp32 -> 8 bf16 (16 B) into LDS.
static __device__ __forceinline__ void stage8f(u16* dst, const float* s) {
    const float4 a = *(const float4*)s;
    const float4 b = *(const float4*)(s + 4);
    u16 tmp[8] = { f2b(a.x), f2b(a.y), f2b(a.z), f2b(a.w),
                   f2b(b.x), f2b(b.y), f2b(b.z), f2b(b.w) };
    *(uint4*)dst = *(const uint4*)tmp;
}

// ---------------------------------------------------------------------------
// K/V projection. grid (chunk, L/64, 2) z=0->K (row-major L x 64),
// z=1->V (TRANSPOSED: 64 dims x L keys). Block 64x64 tile, 4 waves 2x2.
// ---------------------------------------------------------------------------
__global__ __launch_bounds__(256) void kvproj_kernel(
    const float* __restrict__ x,
    const float* __restrict__ Wk, const float* __restrict__ bk,
    const float* __restrict__ Wv, const float* __restrict__ bv,
    u16* __restrict__ Kws, u16* __restrict__ Vws, int bh0)
{
    __shared__ __align__(16) unsigned char sm[10240];
    u16 (*As)[40] = (u16(*)[40])sm;            // 5120 B
    u16 (*Bs)[40] = (u16(*)[40])(sm + 5120);   // 5120 B
    u16 (*Ts)[73] = (u16(*)[73])sm;            // 9344 B (V transpose bounce)

    const int t    = threadIdx.x;
    const int wid  = t >> 6, lane = t & 63;
    const int m15  = lane & 15, quad = lane >> 4;
    const int wm   = wid >> 1, wn = wid & 1;

    const int bh = bh0 + blockIdx.x;
    const int b  = bh >> 3, h = bh & 7;
    const int l0 = blockIdx.y * 64;
    const float* W  = blockIdx.z ? Wv : Wk;
    const float* bi = blockIdx.z ? bv : bk;

    const int lrow = t >> 2;        // 0..63
    const int lcol = (t & 3) * 8;   // 0,8,16,24
    const size_t xrow0 = (size_t)b * L_ + l0;

    f32x4 acc[2][2] = {};

    for (int k0 = 0; k0 < 512; k0 += 32) {
        __syncthreads();
        stage8f(&As[lrow][lcol], x + (xrow0 + lrow) * 512 + k0 + lcol);
        stage8f(&Bs[lrow][lcol], W + (size_t)(h * 64 + lrow) * 512 + k0 + lcol);
        __syncthreads();

        short8 afr[2], bfr[2];
#pragma unroll
        for (int mi = 0; mi < 2; ++mi)
            afr[mi] = *(const short8*)(&As[wm * 32 + mi * 16 + m15][quad * 8]);
#pragma unroll
        for (int ni = 0; ni < 2; ++ni)
            bfr[ni] = *(const short8*)(&Bs[wn * 32 + ni * 16 + m15][quad * 8]);
#pragma unroll
        for (int mi = 0; mi < 2; ++mi)
#pragma unroll
            for (int ni = 0; ni < 2; ++ni)
                acc[mi][ni] = __builtin_amdgcn_mfma_f32_16x16x32_bf16(
                    afr[mi], bfr[ni], acc[mi][ni], 0, 0, 0);
    }

    if (blockIdx.z == 0) {
        // K: direct row-major (L, 64)
        u16* out = Kws + (size_t)blockIdx.x * (L_ * 64);
#pragma unroll
        for (int mi = 0; mi < 2; ++mi)
#pragma unroll
            for (int ni = 0; ni < 2; ++ni) {
                const int d  = wn * 32 + ni * 16 + m15;
                const float bv_ = bi[h * 64 + d];
#pragma unroll
                for (int r = 0; r < 4; ++r) {
                    const int l = l0 + wm * 32 + mi * 16 + quad * 4 + r;
                    out[(size_t)l * 64 + d] = f2b(acc[mi][ni][r] + bv_);
                }
            }
    } else {
        // V: bounce through LDS, store transposed (64 dims x L keys)
        __syncthreads();   // all MFMA LDS reads done before overwrite
#pragma unroll
        for (int mi = 0; mi < 2; ++mi)
#pragma unroll
            for (int ni = 0; ni < 2; ++ni) {
                const int d  = wn * 32 + ni * 16 + m15;
                const float bv_ = bi[h * 64 + d];
#pragma unroll
                for (int r = 0; r < 4; ++r)
                    Ts[wm * 32 + mi * 16 + quad * 4 + r][d] = f2b(acc[mi][ni][r] + bv_);
            }
        __syncthreads();
        u16* Vt = Vws + (size_t)blockIdx.x * ((size_t)64 * L_);
        const int d  = t >> 2;
        const int ls = (t & 3) * 16;
        u16 pk[16];
#pragma unroll
        for (int j = 0; j < 16; ++j) pk[j] = Ts[ls + j][d];
        u16* dst = Vt + (size_t)d * L_ + l0 + ls;
        *(uint4*)dst       = *(const uint4*)pk;
        *(uint4*)(dst + 8) = *(const uint4*)(pk + 8);
    }
}

// ---------------------------------------------------------------------------
// Fused Q-projection + flash attention. grid (L/128, chunk).
// Block = 4 waves; wave w owns q-rows [32w, 32w+32) (2 A-frags).
// LDS phased union: ph1 {xs[128][40], wqs[64][40]} overlays ph2 {Ks, Vts}.
// ---------------------------------------------------------------------------
#define KS_OFF  0
#define VTS_OFF 9216
#define PS_OFF  18432
#define MS_OFF  36864
__global__ __launch_bounds__(256) void attn_kernel(
    const float* __restrict__ x,
    const float* __restrict__ Wq, const float* __restrict__ bq,
    const u16* __restrict__ Kws, const u16* __restrict__ Vws,
    const int* __restrict__ mask,
    float* __restrict__ O, int bh0)
{
    __shared__ __align__(16) unsigned char sm[36864 + 256];
    u16 (*xs)[40]  = (u16(*)[40])sm;                    // ph1, 10240 B
    u16 (*wqs)[40] = (u16(*)[40])(sm + 10240);          // ph1, 5120 B
    u16 (*Ks)[72]  = (u16(*)[72])(sm + KS_OFF);         // ph2, 9216 B [key][dim]
    u16 (*Vts)[72] = (u16(*)[72])(sm + VTS_OFF);        // ph2, 9216 B [dim][key]
    float* Ms      = (float*)(sm + MS_OFF);             // 1.0 = masked

    const int t    = threadIdx.x;
    const int wid  = t >> 6, lane = t & 63;
    const int m15  = lane & 15, quad = lane >> 4;
    u16 (*Psw)[72] = (u16(*)[72])(sm + PS_OFF + wid * (32 * 72 * 2));  // per-wave

    const int bh = bh0 + blockIdx.y;
    const int b  = bh >> 3, h = bh & 7;
    const int q0 = blockIdx.x * 128;
    const u16* Kc  = Kws + (size_t)blockIdx.y * (L_ * 64);
    const u16* Vtc = Vws + (size_t)blockIdx.y * ((size_t)64 * L_);

    // ---- phase 1: Q[128][64] = x[q-tile] @ Wq[h]^T + bq, pre-scaled 1/8 ----
    f32x4 qacc[2][4] = {};
    {
        const int xrow = t >> 2, xcol = (t & 3) * 8;     // wqs mapping
        for (int k0 = 0; k0 < 512; k0 += 32) {
            __syncthreads();
#pragma unroll
            for (int i = 0; i < 2; ++i) {
                const int idx = t + i * 256;             // 0..511
                const int row = idx >> 2, col = (idx & 3) * 8;
                stage8f(&xs[row][col], x + ((size_t)b * L_ + q0 + row) * 512 + k0 + col);
            }
            stage8f(&wqs[xrow][xcol], Wq + (size_t)(h * 64 + xrow) * 512 + k0 + xcol);
            __syncthreads();
            short8 afr[2];
#pragma unroll
            for (int mi = 0; mi < 2; ++mi)
                afr[mi] = *(const short8*)(&xs[wid * 32 + mi * 16 + m15][quad * 8]);
#pragma unroll
            for (int ni = 0; ni < 4; ++ni) {
                const short8 bfr = *(const short8*)(&wqs[ni * 16 + m15][quad * 8]);
#pragma unroll
                for (int mi = 0; mi < 2; ++mi)
                    qacc[mi][ni] = __builtin_amdgcn_mfma_f32_16x16x32_bf16(
                        afr[mi], bfr, qacc[mi][ni], 0, 0, 0);
            }
        }
    }
    // C-layout -> per-wave Ps slice -> A-frags (wave-local, DS in-order)
    short8 qf[2][2];
#pragma unroll
    for (int ni = 0; ni < 4; ++ni) {
        const float bv_ = bq[h * 64 + ni * 16 + m15];
#pragma unroll
        for (int mi = 0; mi < 2; ++mi)
#pragma unroll
            for (int r = 0; r < 4; ++r)
                Psw[mi * 16 + quad * 4 + r][ni * 16 + m15] =
                    f2b((qacc[mi][ni][r] + bv_) * 0.125f);
    }
#pragma unroll
    for (int mi = 0; mi < 2; ++mi)
#pragma unroll
        for (int kc = 0; kc < 2; ++kc)
            qf[mi][kc] = *(const short8*)(&Psw[mi * 16 + m15][kc * 32 + quad * 8]);

    // ---- flash loop over 64-key tiles ----
    float m_i[2][4], l_i[2][4];
#pragma unroll
    for (int mi = 0; mi < 2; ++mi)
#pragma unroll
        for (int r = 0; r < 4; ++r) { m_i[mi][r] = -1e30f; l_i[mi][r] = 0.0f; }
    f32x4 oacc[2][4] = {};

    for (int kt = 0; kt < 64; ++kt) {
        const int k0 = kt * 64;
        __syncthreads();
#pragma unroll
        for (int i = 0; i < 2; ++i) {
            const int c   = t + i * 256;       // 0..511
            const int row = c >> 3;            // key (K) / dim (Vt)
            const int col = (c & 7) * 8;
            *(uint4*)(&Ks [row][col]) = *(const uint4*)(Kc  + (size_t)(k0 + row) * 64 + col);
            *(uint4*)(&Vts[row][col]) = *(const uint4*)(Vtc + (size_t)row * L_ + k0 + col);
        }
        if (t < 64) Ms[t] = (mask[b * L_ + k0 + t] == 0) ? 1.0f : 0.0f;
        __syncthreads();

        // S = (Q/8) K^T, C-layout; masked -> -10000
        float s[2][4][4];
#pragma unroll
        for (int ni = 0; ni < 4; ++ni) {
            short8 kf[2];
#pragma unroll
            for (int kc = 0; kc < 2; ++kc)
                kf[kc] = *(const short8*)(&Ks[ni * 16 + m15][kc * 32 + quad * 8]);
            const float msk = Ms[ni * 16 + m15];
#pragma unroll
            for (int mi = 0; mi < 2; ++mi) {
                f32x4 sa = {};
                sa = __builtin_amdgcn_mfma_f32_16x16x32_bf16(qf[mi][0], kf[0], sa, 0, 0, 0);
                sa = __builtin_amdgcn_mfma_f32_16x16x32_bf16(qf[mi][1], kf[1], sa, 0, 0, 0);
#pragma unroll
                for (int r = 0; r < 4; ++r)
                    s[mi][ni][r] = (msk != 0.0f) ? -10000.0f : sa[r];
            }
        }

        // online softmax per q-row
        float alpha[2][4];
#pragma unroll
        for (int mi = 0; mi < 2; ++mi)
#pragma unroll
            for (int r = 0; r < 4; ++r) {
                float mx = fmaxf(fmaxf(s[mi][0][r], s[mi][1][r]),
                                 fmaxf(s[mi][2][r], s[mi][3][r]));
#pragma unroll
                for (int off = 1; off < 16; off <<= 1)
                    mx = fmaxf(mx, __shfl_xor(mx, off));
                const float mnew = fmaxf(m_i[mi][r], mx);
                alpha[mi][r] = __expf(m_i[mi][r] - mnew);
                m_i[mi][r] = mnew;
                float ss = 0.0f;
#pragma unroll
                for (int ni = 0; ni < 4; ++ni) {
                    const float p = __expf(s[mi][ni][r] - mnew);
                    s[mi][ni][r] = p;
                    ss += p;
                }
#pragma unroll
                for (int off = 1; off < 16; off <<= 1)
                    ss += __shfl_xor(ss, off);
                l_i[mi][r] = l_i[mi][r] * alpha[mi][r] + ss;
            }

        // P: C-layout -> per-wave Ps -> A-frags
#pragma unroll
        for (int mi = 0; mi < 2; ++mi)
#pragma unroll
            for (int ni = 0; ni < 4; ++ni)
#pragma unroll
                for (int r = 0; r < 4; ++r)
                    Psw[mi * 16 + quad * 4 + r][ni * 16 + m15] = f2b(s[mi][ni][r]);
        short8 pf[2][2];
#pragma unroll
        for (int mi = 0; mi < 2; ++mi)
#pragma unroll
            for (int kc = 0; kc < 2; ++kc)
                pf[mi][kc] = *(const short8*)(&Psw[mi * 16 + m15][kc * 32 + quad * 8]);

        // O = alpha*O + P V
#pragma unroll
        for (int ni = 0; ni < 4; ++ni) {
            short8 vf[2];
#pragma unroll
            for (int kc = 0; kc < 2; ++kc)
                vf[kc] = *(const short8*)(&Vts[ni * 16 + m15][kc * 32 + quad * 8]);
#pragma unroll
            for (int mi = 0; mi < 2; ++mi) {
#pragma unroll
                for (int r = 0; r < 4; ++r) oacc[mi][ni][r] *= alpha[mi][r];
                oacc[mi][ni] = __builtin_amdgcn_mfma_f32_16x16x32_bf16(
                    pf[mi][0], vf[0], oacc[mi][ni], 0, 0, 0);
                oacc[mi][ni] = __builtin_amdgcn_mfma_f32_16x16x32_bf16(
                    pf[mi][1], vf[1], oacc[mi][ni], 0, 0, 0);
            }
        }
    }

    // epilogue: O /= l -> fp32 (B, L, 512)
#pragma unroll
    for (int mi = 0; mi < 2; ++mi)
#pragma unroll
        for (int ni = 0; ni < 4; ++ni)
#pragma unroll
            for (int r = 0; r < 4; ++r) {
                const int qrow = q0 + wid * 32 + mi * 16 + quad * 4 + r;
                O[((size_t)b * L_ + qrow) * 512 + h * 64 + ni * 16 + m15] =
                    oacc[mi][ni][r] / l_i[mi][r];
            }
}

// ---------------------------------------------------------------------------
// In-place fp32 output projection: AO = AO @ Wo^T + bo, (M,512).
// ---------------------------------------------------------------------------
__global__ __launch_bounds__(256) void outproj_kernel(
    float* __restrict__ AO,
    const float* __restrict__ Wo, const float* __restrict__ bo)
{
    __shared__ __align__(16) u16 As[32][520];
    __shared__ __align__(16) u16 Ws_[64][40];

    const int t    = threadIdx.x;
    const int wid  = t >> 6, lane = t & 63;
    const int m15  = lane & 15, quad = lane >> 4;
    const int wm   = wid >> 1, wn = wid & 1;
    const int bm   = blockIdx.x * 32;

#pragma unroll
    for (int it = 0; it < 8; ++it) {
        const int idx = t + it * 256;            // 0..2047
        const int row = idx >> 6, c8 = (idx & 63) * 8;
        stage8f(&As[row][c8], AO + (size_t)(bm + row) * 512 + c8);
    }
    const int lrow = t >> 2;
    const int lcol = (t & 3) * 8;
    __syncthreads();

    for (int n0 = 0; n0 < 512; n0 += 64) {
        f32x4 acc[2] = {};
        for (int k0 = 0; k0 < 512; k0 += 32) {
            __syncthreads();
            stage8f(&Ws_[lrow][lcol], Wo + (size_t)(n0 + lrow) * 512 + k0 + lcol);
            __syncthreads();
            const short8 afr = *(const short8*)(&As[wm * 16 + m15][k0 + quad * 8]);
#pragma unroll
            for (int ni = 0; ni < 2; ++ni) {
                const short8 bfr = *(const short8*)(&Ws_[wn * 32 + ni * 16 + m15][quad * 8]);
                acc[ni] = __builtin_amdgcn_mfma_f32_16x16x32_bf16(afr, bfr, acc[ni], 0, 0, 0);
            }
        }
#pragma unroll
        for (int ni = 0; ni < 2; ++ni) {
            const int col = n0 + wn * 32 + ni * 16 + m15;
            const float bv_ = bo[col];
#pragma unroll
            for (int r = 0; r < 4; ++r) {
                const int row = bm + wm * 16 + quad * 4 + r;
                AO[(size_t)row * 512 + col] = acc[ni][r] + bv_;
            }
        }
    }
}

extern "C" void kernel_launch(void* const* d_in, const int* in_sizes, int n_in,
                              void* d_out, int out_size, void* d_ws, size_t ws_size,
                              hipStream_t stream) {
    const float* x    = (const float*)d_in[0];
    const int*   mask = (const int*)d_in[1];
    const float* Wq = (const float*)d_in[2]; const float* bq = (const float*)d_in[3];
    const float* Wk = (const float*)d_in[4]; const float* bk = (const float*)d_in[5];
    const float* Wv = (const float*)d_in[6]; const float* bv = (const float*)d_in[7];
    const float* Wo = (const float*)d_in[8]; const float* bo = (const float*)d_in[9];

    float* out = (float*)d_out;
    u16*   ws  = (u16*)d_ws;

    // bf16 K+V per bh = 1 MiB; adaptive chunk (ws certified >= 3 MiB).
    const size_t per_bh = (size_t)2 * L_ * 64 * 2;
    int chunk = 16;
    while (chunk > 1 && (size_t)chunk * per_bh > ws_size) chunk >>= 1;

    u16* Kws = ws;
    u16* Vws = Kws + (size_t)chunk * (L_ * 64);

    for (int bh0 = 0; bh0 < BH_; bh0 += chunk) {
        kvproj_kernel<<<dim3(chunk, L_ / 64, 2), 256, 0, stream>>>(
            x, Wk, bk, Wv, bv, Kws, Vws, bh0);
        attn_kernel<<<dim3(L_ / 128, chunk), 256, 0, stream>>>(
            x, Wq, bq, Kws, Vws, mask, out, bh0);
    }
    outproj_kernel<<<dim3(M_ / 32), 256, 0, stream>>>(out, Wo, bo);
}

// Round 15
// 413.636 us; speedup vs baseline: 26.6011x; 1.0706x over previous
//
#include <hip/hip_runtime.h>

// Round 15: attn occupancy + latency. (1) 512-thread attn blocks: 8 waves x
// 16 q-rows (q-tile 128) -> 16 waves/CU (was 8; grid is 2 blocks/CU fixed).
// (2) Register prefetch of K/Vt/mask across the k-loop barrier. kvproj keeps
// the V pre-transpose; outproj unchanged. fp32 I/O, bf16 MFMA compute.

#define B_  2
#define L_  4096
#define D_  512
#define H_  8
#define BH_ 16
#define M_  8192

typedef __attribute__((ext_vector_type(8))) short short8;    // 8 bf16 = 4 VGPR
typedef __attribute__((ext_vector_type(4))) float f32x4;
typedef unsigned short u16;

static __device__ __forceinline__ u16 f2b(float f) {
    union { float f; unsigned i; } x; x.f = f;
    unsigned r = x.i + 0x7fff + ((x.i >> 16) & 1);   // RNE
    return (u16)(r >> 16);
}

// Stage 8 consecutive fp32 -> 8 bf16 (16 B) into LDS.
static __device__ __forceinline__ void stage8f(u16* dst, const float* s) {
    const float4 a = *(const float4*)s;
    const float4 b = *(const float4*)(s + 4);
    u16 tmp[8] = { f2b(a.x), f2b(a.y), f2b(a.z), f2b(a.w),
                   f2b(b.x), f2b(b.y), f2b(b.z), f2b(b.w) };
    *(uint4*)dst = *(const uint4*)tmp;
}

// ---------------------------------------------------------------------------
// K/V projection. grid (chunk, L/64, 2) z=0->K (row-major L x 64),
// z=1->V (TRANSPOSED: 64 dims x L keys). Block 64x64 tile, 4 waves 2x2.
// ---------------------------------------------------------------------------
__global__ __launch_bounds__(256) void kvproj_kernel(
    const float* __restrict__ x,
    const float* __restrict__ Wk, const float* __restrict__ bk,
    const float* __restrict__ Wv, const float* __restrict__ bv,
    u16* __restrict__ Kws, u16* __restrict__ Vws, int bh0)
{
    __shared__ __align__(16) unsigned char sm[10240];
    u16 (*As)[40] = (u16(*)[40])sm;            // 5120 B
    u16 (*Bs)[40] = (u16(*)[40])(sm + 5120);   // 5120 B
    u16 (*Ts)[73] = (u16(*)[73])sm;            // 9344 B (V transpose bounce)

    const int t    = threadIdx.x;
    const int wid  = t >> 6, lane = t & 63;
    const int m15  = lane & 15, quad = lane >> 4;
    const int wm   = wid >> 1, wn = wid & 1;

    const int bh = bh0 + blockIdx.x;
    const int b  = bh >> 3, h = bh & 7;
    const int l0 = blockIdx.y * 64;
    const float* W  = blockIdx.z ? Wv : Wk;
    const float* bi = blockIdx.z ? bv : bk;

    const int lrow = t >> 2;        // 0..63
    const int lcol = (t & 3) * 8;   // 0,8,16,24
    const size_t xrow0 = (size_t)b * L_ + l0;

    f32x4 acc[2][2] = {};

    for (int k0 = 0; k0 < 512; k0 += 32) {
        __syncthreads();
        stage8f(&As[lrow][lcol], x + (xrow0 + lrow) * 512 + k0 + lcol);
        stage8f(&Bs[lrow][lcol], W + (size_t)(h * 64 + lrow) * 512 + k0 + lcol);
        __syncthreads();

        short8 afr[2], bfr[2];
#pragma unroll
        for (int mi = 0; mi < 2; ++mi)
            afr[mi] = *(const short8*)(&As[wm * 32 + mi * 16 + m15][quad * 8]);
#pragma unroll
        for (int ni = 0; ni < 2; ++ni)
            bfr[ni] = *(const short8*)(&Bs[wn * 32 + ni * 16 + m15][quad * 8]);
#pragma unroll
        for (int mi = 0; mi < 2; ++mi)
#pragma unroll
            for (int ni = 0; ni < 2; ++ni)
                acc[mi][ni] = __builtin_amdgcn_mfma_f32_16x16x32_bf16(
                    afr[mi], bfr[ni], acc[mi][ni], 0, 0, 0);
    }

    if (blockIdx.z == 0) {
        u16* out = Kws + (size_t)blockIdx.x * (L_ * 64);
#pragma unroll
        for (int mi = 0; mi < 2; ++mi)
#pragma unroll
            for (int ni = 0; ni < 2; ++ni) {
                const int d  = wn * 32 + ni * 16 + m15;
                const float bv_ = bi[h * 64 + d];
#pragma unroll
                for (int r = 0; r < 4; ++r) {
                    const int l = l0 + wm * 32 + mi * 16 + quad * 4 + r;
                    out[(size_t)l * 64 + d] = f2b(acc[mi][ni][r] + bv_);
                }
            }
    } else {
        __syncthreads();   // all MFMA LDS reads done before overwrite
#pragma unroll
        for (int mi = 0; mi < 2; ++mi)
#pragma unroll
            for (int ni = 0; ni < 2; ++ni) {
                const int d  = wn * 32 + ni * 16 + m15;
                const float bv_ = bi[h * 64 + d];
#pragma unroll
                for (int r = 0; r < 4; ++r)
                    Ts[wm * 32 + mi * 16 + quad * 4 + r][d] = f2b(acc[mi][ni][r] + bv_);
            }
        __syncthreads();
        u16* Vt = Vws + (size_t)blockIdx.x * ((size_t)64 * L_);
        const int d  = t >> 2;
        const int ls = (t & 3) * 16;
        u16 pk[16];
#pragma unroll
        for (int j = 0; j < 16; ++j) pk[j] = Ts[ls + j][d];
        u16* dst = Vt + (size_t)d * L_ + l0 + ls;
        *(uint4*)dst       = *(const uint4*)pk;
        *(uint4*)(dst + 8) = *(const uint4*)(pk + 8);
    }
}

// ---------------------------------------------------------------------------
// Fused Q-projection + flash attention. grid (L/128, chunk), block 512.
// 8 waves; wave w owns q-rows [16w, 16w+16). Register-prefetched k-loop.
// LDS phased union: ph1 {xs[128][40], wqs[64][40]} overlays ph2 {Ks, Vts}.
// ---------------------------------------------------------------------------
#define KS_OFF  0
#define VTS_OFF 9216
#define PS_OFF  18432
#define MS_OFF  36864
__global__ __launch_bounds__(512) void attn_kernel(
    const float* __restrict__ x,
    const float* __restrict__ Wq, const float* __restrict__ bq,
    const u16* __restrict__ Kws, const u16* __restrict__ Vws,
    const int* __restrict__ mask,
    float* __restrict__ O, int bh0)
{
    __shared__ __align__(16) unsigned char sm[36864 + 256];
    u16 (*xs)[40]  = (u16(*)[40])sm;                    // ph1, 10240 B
    u16 (*wqs)[40] = (u16(*)[40])(sm + 10240);          // ph1, 5120 B
    u16 (*Ks)[72]  = (u16(*)[72])(sm + KS_OFF);         // ph2, 9216 B [key][dim]
    u16 (*Vts)[72] = (u16(*)[72])(sm + VTS_OFF);        // ph2, 9216 B [dim][key]
    float* Ms      = (float*)(sm + MS_OFF);             // 1.0 = masked

    const int t    = threadIdx.x;
    const int wid  = t >> 6, lane = t & 63;
    const int m15  = lane & 15, quad = lane >> 4;
    u16 (*Psw)[72] = (u16(*)[72])(sm + PS_OFF + wid * (16 * 72 * 2));  // per-wave

    const int bh = bh0 + blockIdx.y;
    const int b  = bh >> 3, h = bh & 7;
    const int q0 = blockIdx.x * 128;
    const u16* Kc  = Kws + (size_t)blockIdx.y * (L_ * 64);
    const u16* Vtc = Vws + (size_t)blockIdx.y * ((size_t)64 * L_);

    // ---- phase 1: Q[128][64] = x[q-tile] @ Wq[h]^T + bq, pre-scaled 1/8 ----
    f32x4 qacc[4] = {};
    {
        const int xr = t >> 2, xc = (t & 3) * 8;         // 128 rows x 4 groups
        for (int k0 = 0; k0 < 512; k0 += 32) {
            __syncthreads();
            stage8f(&xs[xr][xc], x + ((size_t)b * L_ + q0 + xr) * 512 + k0 + xc);
            if (t < 256)
                stage8f(&wqs[xr][xc], Wq + (size_t)(h * 64 + xr) * 512 + k0 + xc);
            __syncthreads();
            const short8 afr = *(const short8*)(&xs[wid * 16 + m15][quad * 8]);
#pragma unroll
            for (int ni = 0; ni < 4; ++ni) {
                const short8 bfr = *(const short8*)(&wqs[ni * 16 + m15][quad * 8]);
                qacc[ni] = __builtin_amdgcn_mfma_f32_16x16x32_bf16(afr, bfr, qacc[ni], 0, 0, 0);
            }
        }
    }
    // C-layout -> per-wave Ps slice -> A-frag (wave-local, DS in-order)
    short8 qf[2];
#pragma unroll
    for (int ni = 0; ni < 4; ++ni) {
        const float bv_ = bq[h * 64 + ni * 16 + m15];
#pragma unroll
        for (int r = 0; r < 4; ++r)
            Psw[quad * 4 + r][ni * 16 + m15] = f2b((qacc[ni][r] + bv_) * 0.125f);
    }
#pragma unroll
    for (int kc = 0; kc < 2; ++kc)
        qf[kc] = *(const short8*)(&Psw[m15][kc * 32 + quad * 8]);

    // ---- flash loop over 64-key tiles, register-prefetched ----
    const int srow = t >> 3;            // 0..63
    const int scol = (t & 7) * 8;       // 0..56
    uint4 kreg = *(const uint4*)(Kc  + (size_t)srow * 64 + scol);
    uint4 vreg = *(const uint4*)(Vtc + (size_t)srow * L_ + scol);
    int   mreg = (t < 64) ? mask[b * L_ + t] : 0;

    float m_i[4], l_i[4];
#pragma unroll
    for (int r = 0; r < 4; ++r) { m_i[r] = -1e30f; l_i[r] = 0.0f; }
    f32x4 oacc[4] = {};

    for (int kt = 0; kt < 64; ++kt) {
        __syncthreads();                 // prior tile's LDS reads done
        *(uint4*)(&Ks [srow][scol]) = kreg;
        *(uint4*)(&Vts[srow][scol]) = vreg;
        if (t < 64) Ms[t] = (mreg == 0) ? 1.0f : 0.0f;
        __syncthreads();                 // tile kt visible
        if (kt + 1 < 64) {               // prefetch kt+1 (overlaps compute)
            const int k1 = (kt + 1) * 64;
            kreg = *(const uint4*)(Kc  + (size_t)(k1 + srow) * 64 + scol);
            vreg = *(const uint4*)(Vtc + (size_t)srow * L_ + k1 + scol);
            if (t < 64) mreg = mask[b * L_ + k1 + t];
        }

        // S = (Q/8) K^T, C-layout; masked -> -10000
        float s[4][4];
#pragma unroll
        for (int ni = 0; ni < 4; ++ni) {
            f32x4 sa = {};
#pragma unroll
            for (int kc = 0; kc < 2; ++kc) {
                const short8 kf = *(const short8*)(&Ks[ni * 16 + m15][kc * 32 + quad * 8]);
                sa = __builtin_amdgcn_mfma_f32_16x16x32_bf16(qf[kc], kf, sa, 0, 0, 0);
            }
            const float msk = Ms[ni * 16 + m15];
#pragma unroll
            for (int r = 0; r < 4; ++r)
                s[ni][r] = (msk != 0.0f) ? -10000.0f : sa[r];
        }

        // online softmax per q-row (16 lanes of a quad share a row)
        float alpha[4];
#pragma unroll
        for (int r = 0; r < 4; ++r) {
            float mx = fmaxf(fmaxf(s[0][r], s[1][r]), fmaxf(s[2][r], s[3][r]));
#pragma unroll
            for (int off = 1; off < 16; off <<= 1)
                mx = fmaxf(mx, __shfl_xor(mx, off));
            const float mnew = fmaxf(m_i[r], mx);
            alpha[r] = __expf(m_i[r] - mnew);
            m_i[r] = mnew;
            float ss = 0.0f;
#pragma unroll
            for (int ni = 0; ni < 4; ++ni) {
                const float p = __expf(s[ni][r] - mnew);
                s[ni][r] = p;
                ss += p;
            }
#pragma unroll
            for (int off = 1; off < 16; off <<= 1)
                ss += __shfl_xor(ss, off);
            l_i[r] = l_i[r] * alpha[r] + ss;
        }

        // P: C-layout -> per-wave Ps -> A-frags
#pragma unroll
        for (int ni = 0; ni < 4; ++ni)
#pragma unroll
            for (int r = 0; r < 4; ++r)
                Psw[quad * 4 + r][ni * 16 + m15] = f2b(s[ni][r]);
        short8 pf[2];
#pragma unroll
        for (int kc = 0; kc < 2; ++kc)
            pf[kc] = *(const short8*)(&Psw[m15][kc * 32 + quad * 8]);

        // O = alpha*O + P V
#pragma unroll
        for (int ni = 0; ni < 4; ++ni) {
#pragma unroll
            for (int r = 0; r < 4; ++r) oacc[ni][r] *= alpha[r];
#pragma unroll
            for (int kc = 0; kc < 2; ++kc) {
                const short8 vf = *(const short8*)(&Vts[ni * 16 + m15][kc * 32 + quad * 8]);
                oacc[ni] = __builtin_amdgcn_mfma_f32_16x16x32_bf16(pf[kc], vf, oacc[ni], 0, 0, 0);
            }
        }
    }

    // epilogue: O /= l -> fp32 (B, L, 512)
#pragma unroll
    for (int ni = 0; ni < 4; ++ni)
#pragma unroll
        for (int r = 0; r < 4; ++r) {
            const int qrow = q0 + wid * 16 + quad * 4 + r;
            O[((size_t)b * L_ + qrow) * 512 + h * 64 + ni * 16 + m15] =
                oacc[ni][r] / l_i[r];
        }
}

// ---------------------------------------------------------------------------
// In-place fp32 output projection: AO = AO @ Wo^T + bo, (M,512).
// ---------------------------------------------------------------------------
__global__ __launch_bounds__(256) void outproj_kernel(
    float* __restrict__ AO,
    const float* __restrict__ Wo, const float* __restrict__ bo)
{
    __shared__ __align__(16) u16 As[32][520];
    __shared__ __align__(16) u16 Ws_[64][40];

    const int t    = threadIdx.x;
    const int wid  = t >> 6, lane = t & 63;
    const int m15  = lane & 15, quad = lane >> 4;
    const int wm   = wid >> 1, wn = wid & 1;
    const int bm   = blockIdx.x * 32;

#pragma unroll
    for (int it = 0; it < 8; ++it) {
        const int idx = t + it * 256;            // 0..2047
        const int row = idx >> 6, c8 = (idx & 63) * 8;
        stage8f(&As[row][c8], AO + (size_t)(bm + row) * 512 + c8);
    }
    const int lrow = t >> 2;
    const int lcol = (t & 3) * 8;
    __syncthreads();

    for (int n0 = 0; n0 < 512; n0 += 64) {
        f32x4 acc[2] = {};
        for (int k0 = 0; k0 < 512; k0 += 32) {
            __syncthreads();
            stage8f(&Ws_[lrow][lcol], Wo + (size_t)(n0 + lrow) * 512 + k0 + lcol);
            __syncthreads();
            const short8 afr = *(const short8*)(&As[wm * 16 + m15][k0 + quad * 8]);
#pragma unroll
            for (int ni = 0; ni < 2; ++ni) {
                const short8 bfr = *(const short8*)(&Ws_[wn * 32 + ni * 16 + m15][quad * 8]);
                acc[ni] = __builtin_amdgcn_mfma_f32_16x16x32_bf16(afr, bfr, acc[ni], 0, 0, 0);
            }
        }
#pragma unroll
        for (int ni = 0; ni < 2; ++ni) {
            const int col = n0 + wn * 32 + ni * 16 + m15;
            const float bv_ = bo[col];
#pragma unroll
            for (int r = 0; r < 4; ++r) {
                const int row = bm + wm * 16 + quad * 4 + r;
                AO[(size_t)row * 512 + col] = acc[ni][r] + bv_;
            }
        }
    }
}

extern "C" void kernel_launch(void* const* d_in, const int* in_sizes, int n_in,
                              void* d_out, int out_size, void* d_ws, size_t ws_size,
                              hipStream_t stream) {
    const float* x    = (const float*)d_in[0];
    const int*   mask = (const int*)d_in[1];
    const float* Wq = (const float*)d_in[2]; const float* bq = (const float*)d_in[3];
    const float* Wk = (const float*)d_in[4]; const float* bk = (const float*)d_in[5];
    const float* Wv = (const float*)d_in[6]; const float* bv = (const float*)d_in[7];
    const float* Wo = (const float*)d_in[8]; const float* bo = (const float*)d_in[9];

    float* out = (float*)d_out;
    u16*   ws  = (u16*)d_ws;

    // bf16 K+V per bh = 1 MiB; adaptive chunk (ws certified >= 16 MiB).
    const size_t per_bh = (size_t)2 * L_ * 64 * 2;
    int chunk = 16;
    while (chunk > 1 && (size_t)chunk * per_bh > ws_size) chunk >>= 1;

    u16* Kws = ws;
    u16* Vws = Kws + (size_t)chunk * (L_ * 64);

    for (int bh0 = 0; bh0 < BH_; bh0 += chunk) {
        kvproj_kernel<<<dim3(chunk, L_ / 64, 2), 256, 0, stream>>>(
            x, Wk, bk, Wv, bv, Kws, Vws, bh0);
        attn_kernel<<<dim3(L_ / 128, chunk), 512, 0, stream>>>(
            x, Wq, bq, Kws, Vws, mask, out, bh0);
    }
    outproj_kernel<<<dim3(M_ / 32), 256, 0, stream>>>(out, Wo, bo);
}